// Round 11
// baseline (251.437 us; speedup 1.0000x reference)
//
#include <hip/hip_runtime.h>

#define NB 8192
#define NT 50

typedef short short8 __attribute__((ext_vector_type(8)));
typedef float f32x4 __attribute__((ext_vector_type(4)));

__device__ __forceinline__ float leaky(float x) { return x > 0.0f ? x : 0.3f * x; }

__device__ __forceinline__ unsigned short bf16rn(float v) {
    unsigned int u = __float_as_uint(v);
    unsigned int r = u + 0x7FFFu + ((u >> 16) & 1u);
    return (unsigned short)(r >> 16);
}
__device__ __forceinline__ float bf16tof(unsigned short h) {
    return __uint_as_float(((unsigned int)h) << 16);
}
__device__ __forceinline__ float frcp(float x) { return __builtin_amdgcn_rcpf(x); }

struct St {
    float ego_v, ego_a, ego_x, disp;
    float ef_dv, ef_dx, em_dv, em_dx;
    float fa, fv, m0, m1, m2;
};
struct Par { float tg, jam, amax, inv_v0, inv_gd; };

__device__ __forceinline__ void init_state(St& s, const float* idm_s,
                                           const float* merger_cs, int bm) {
    const float* sr = idm_s + (size_t)bm * 714;     // 51*14
    const float* mr = merger_cs + (size_t)bm * 150;
    s.ego_v = sr[0]; s.ego_a = sr[11]; s.ego_x = sr[3]; s.disp = 0.0f;
    const float fv0 = sr[1], mv0 = sr[2], fx0 = sr[4], mx0 = sr[5];
    s.fa = sr[12];
    const float me0 = sr[13];
    s.fv = fv0;
    s.ef_dx = fx0 - s.ego_x;
    s.em_dx = (mx0 - s.ego_x) * me0 + (1.0f - me0) * 100.0f;
    s.ef_dv = s.ego_v - fv0;
    s.em_dv = (s.ego_v - mv0) * me0;
    s.m0 = mr[0]; s.m1 = mr[1]; s.m2 = mr[2];
}

__device__ __forceinline__ void init_par(Par& p, const float* idm_params, int bm) {
    p.tg   = idm_params[bm * 5 + 1];
    p.jam  = idm_params[bm * 5 + 2];
    p.amax = idm_params[bm * 5 + 3];
    p.inv_v0 = 1.0f / idm_params[bm * 5 + 0];
    p.inv_gd = 1.0f / (2.0f * sqrtf(p.amax * idm_params[bm * 5 + 4]));
}

__device__ __forceinline__ f32x4 hpre_calc(int bm, int colbase,
                                           const float* __restrict__ W1,
                                           const float* __restrict__ b1,
                                           const float* __restrict__ proj,
                                           const float* __restrict__ ench,
                                           const float* __restrict__ smean,
                                           const float* __restrict__ svar) {
    f32x4 hp = *(const f32x4*)&b1[colbase];
    const float* xl0 = proj + (size_t)bm * 128;
    const float* xl1 = ench + (size_t)bm * 128;
    #pragma unroll 2
    for (int r0 = 0; r0 < 128; r0 += 4) {
        const f32x4 x = *(const f32x4*)&xl0[r0];
        #pragma unroll
        for (int j = 0; j < 4; ++j) {
            const f32x4 wq = *(const f32x4*)&W1[(r0 + j) * 128 + colbase];
            hp += x[j] * wq;
        }
    }
    #pragma unroll 2
    for (int r0 = 0; r0 < 128; r0 += 4) {
        const f32x4 x = *(const f32x4*)&xl1[r0];
        #pragma unroll
        for (int j = 0; j < 4; ++j) {
            const f32x4 wq = *(const f32x4*)&W1[(128 + r0 + j) * 128 + colbase];
            hp += x[j] * wq;
        }
    }
    #pragma unroll
    for (int rr = 0; rr < 8; ++rr) {   // fold -(mean*inv_std)@W1env
        const float c = smean[rr] * (1.0f / sqrtf(svar[rr]));
        const f32x4 wq = *(const f32x4*)&W1[(256 + rr) * 128 + colbase];
        hp -= c * wq;
    }
    return hp;
}

extern "C" __global__ __launch_bounds__(512, 2)
void idm_rollout_kernel(const float* __restrict__ idm_params,
                        const float* __restrict__ proj_latent,
                        const float* __restrict__ enc_h,
                        const float* __restrict__ idm_s,
                        const float* __restrict__ merger_cs,
                        const float* __restrict__ scaler_mean,
                        const float* __restrict__ scaler_var,
                        const float* __restrict__ W1,
                        const float* __restrict__ b1,
                        const float* __restrict__ W2,
                        const float* __restrict__ b2,
                        const float* __restrict__ Wf,
                        const float* __restrict__ bfp,
                        const float* __restrict__ Wm,
                        const float* __restrict__ bmp,
                        float* __restrict__ out)
{
    __shared__ __align__(16) short s_a[2][4][3][64][8];    // 24 KB (per group)
    __shared__ __align__(16) short s_w2l2[4][512][8];      // 32 KB
    __shared__ __align__(16) float s_w1d[11][128];         // 5.5 KB
    __shared__ __align__(16) float s_part[2][16][20];      // 2.5 KB

    const int tid = threadIdx.x;       // 0..511
    const int w   = tid >> 6;          // wave = jtile
    const int l   = tid & 63;
    const int lm  = l & 15;
    const int lq  = l >> 4;
    const int b0  = blockIdx.x * 32;
    const int bm0 = b0 + lm;           // group-0 element
    const int bm1 = b0 + 16 + lm;      // group-1 element
    const int colbase = w * 16 + lq * 4;

    // ---- stage dynamic W1 rows; env rows scaled by inv_std ----
    for (int idx = tid; idx < 11 * 128; idx += 512) {
        const int r = idx >> 7, c = idx & 127;
        float wv_ = W1[(256 + r) * 128 + c];
        if (r < 8) wv_ *= 1.0f / sqrtf(scaler_var[r]);
        s_w1d[r][c] = wv_;
    }

    // ---- W2^T A-frags: lvl0/1 regs, lvl2 per-thread LDS ----
    short8 W2T0[4], W2T1[4];
    #pragma unroll
    for (int kc = 0; kc < 4; ++kc) {
        short8 l2;
        #pragma unroll
        for (int e = 0; e < 8; ++e) {
            const int k = kc * 32 + lq * 8 + e;
            const float v = W2[k * 128 + w * 16 + lm];
            const unsigned short q0 = bf16rn(v);
            const float r1 = v - bf16tof(q0);
            const unsigned short q1 = bf16rn(r1);
            W2T0[kc][e] = (short)q0; W2T1[kc][e] = (short)q1;
            l2[e] = (short)bf16rn(r1 - bf16tof(q1));
        }
        *(short8*)&s_w2l2[kc][tid][0] = l2;
    }

    // ---- head constants (same columns for both groups) ----
    const f32x4 b2r = *(const f32x4*)&b2[colbase];
    const f32x4 wfr = *(const f32x4*)&Wf[colbase];
    const f32x4 wmr = *(const f32x4*)&Wm[colbase];
    const float bfv = bfp[0];
    const float bmv = bmp[0];

    // ---- hpre + state for both groups ----
    const f32x4 hp0 = hpre_calc(bm0, colbase, W1, b1, proj_latent, enc_h,
                                scaler_mean, scaler_var);
    const f32x4 hp1 = hpre_calc(bm1, colbase, W1, b1, proj_latent, enc_h,
                                scaler_mean, scaler_var);
    St st0, st1; Par pp0, pp1;
    init_state(st0, idm_s, merger_cs, bm0);
    init_state(st1, idm_s, merger_cs, bm1);
    init_par(pp0, idm_params, bm0);
    init_par(pp1, idm_params, bm1);

    float* out_disp = out;
    float* out_act  = out + NB * 51;
    float* out_fat  = out + NB * (51 + 50);
    float* out_mat  = out + NB * (51 + 100);
    if (tid < 16) { out_disp[bm0 * 51] = 0.0f; out_disp[bm1 * 51] = 0.0f; }

    // producer slot for s_a writes (verified round-10 mapping)
    const int kcw = w >> 1;
    const int Lw  = lm + 16 * ((w & 1) * 2 + (lq >> 1));
    const int e0w = (lq & 1) * 4;

    // ---- phase macros (capture ambient locals; all indices static) ----
#define PHASE_A(G, S, HP) do {                                               \
    float ev_[11];                                                           \
    ev_[0] = (S).ego_a; ev_[1] = (S).fa;    ev_[2] = (S).ego_v;              \
    ev_[3] = (S).fv;    ev_[4] = (S).ef_dv; ev_[5] = (S).ef_dx;              \
    ev_[6] = (S).em_dv; ev_[7] = (S).em_dx;                                  \
    ev_[8] = (S).m0;    ev_[9] = (S).m1;    ev_[10] = (S).m2;                \
    f32x4 hq_ = (HP);                                                        \
    _Pragma("unroll")                                                        \
    for (int r_ = 0; r_ < 11; ++r_) {                                        \
        const f32x4 wq_ = *(const f32x4*)&s_w1d[r_][colbase];                \
        hq_ += ev_[r_] * wq_;                                                \
    }                                                                        \
    const float h0_ = leaky(hq_.x), h1_ = leaky(hq_.y);                      \
    const float h2_ = leaky(hq_.z), h3_ = leaky(hq_.w);                      \
    const unsigned int HM_ = 0xFFFF0000u;                                    \
    unsigned int ua_ = __float_as_uint(h0_), ub_ = __float_as_uint(h1_);     \
    unsigned int uc_ = __float_as_uint(h2_), ud_ = __float_as_uint(h3_);     \
    const unsigned int w00_ = (ua_ >> 16) | (ub_ & HM_);                     \
    const unsigned int w01_ = (uc_ >> 16) | (ud_ & HM_);                     \
    const float r1a_ = h0_ - __uint_as_float(ua_ & HM_);                     \
    const float r1b_ = h1_ - __uint_as_float(ub_ & HM_);                     \
    const float r1c_ = h2_ - __uint_as_float(uc_ & HM_);                     \
    const float r1d_ = h3_ - __uint_as_float(ud_ & HM_);                     \
    ua_ = __float_as_uint(r1a_); ub_ = __float_as_uint(r1b_);                \
    uc_ = __float_as_uint(r1c_); ud_ = __float_as_uint(r1d_);                \
    const unsigned int w10_ = (ua_ >> 16) | (ub_ & HM_);                     \
    const unsigned int w11_ = (uc_ >> 16) | (ud_ & HM_);                     \
    const float r2a_ = r1a_ - __uint_as_float(ua_ & HM_);                    \
    const float r2b_ = r1b_ - __uint_as_float(ub_ & HM_);                    \
    const float r2c_ = r1c_ - __uint_as_float(uc_ & HM_);                    \
    const float r2d_ = r1d_ - __uint_as_float(ud_ & HM_);                    \
    const unsigned int w20_ = (__float_as_uint(r2a_) >> 16) | (__float_as_uint(r2b_) & HM_); \
    const unsigned int w21_ = (__float_as_uint(r2c_) >> 16) | (__float_as_uint(r2d_) & HM_); \
    *(uint2*)&s_a[G][kcw][0][Lw][e0w] = make_uint2(w00_, w01_);              \
    *(uint2*)&s_a[G][kcw][1][Lw][e0w] = make_uint2(w10_, w11_);              \
    *(uint2*)&s_a[G][kcw][2][Lw][e0w] = make_uint2(w20_, w21_);              \
} while (0)

#define PHASE_B(G) do {                                                      \
    f32x4 aA_ = {0,0,0,0}, aB_ = {0,0,0,0}, aC_ = {0,0,0,0};                 \
    _Pragma("unroll")                                                        \
    for (int kc_ = 0; kc_ < 4; ++kc_) {                                      \
        const short8 x0_ = *(const short8*)&s_a[G][kc_][0][l][0];            \
        const short8 x1_ = *(const short8*)&s_a[G][kc_][1][l][0];            \
        const short8 x2_ = *(const short8*)&s_a[G][kc_][2][l][0];            \
        const short8 wl2_ = *(const short8*)&s_w2l2[kc_][tid][0];            \
        aA_ = __builtin_amdgcn_mfma_f32_16x16x32_bf16(W2T0[kc_], x0_, aA_, 0, 0, 0); \
        aB_ = __builtin_amdgcn_mfma_f32_16x16x32_bf16(W2T0[kc_], x1_, aB_, 0, 0, 0); \
        aB_ = __builtin_amdgcn_mfma_f32_16x16x32_bf16(W2T1[kc_], x0_, aB_, 0, 0, 0); \
        aC_ = __builtin_amdgcn_mfma_f32_16x16x32_bf16(W2T1[kc_], x1_, aC_, 0, 0, 0); \
        aC_ = __builtin_amdgcn_mfma_f32_16x16x32_bf16(W2T0[kc_], x2_, aC_, 0, 0, 0); \
        aC_ = __builtin_amdgcn_mfma_f32_16x16x32_bf16(wl2_,     x0_, aC_, 0, 0, 0); \
    }                                                                        \
    float fsc_ = 0.0f, msc_ = 0.0f;                                          \
    _Pragma("unroll")                                                        \
    for (int r_ = 0; r_ < 4; ++r_) {                                         \
        const float h2_ = leaky(aA_[r_] + aB_[r_] + aC_[r_] + b2r[r_]);      \
        fsc_ += h2_ * wfr[r_];                                               \
        msc_ += h2_ * wmr[r_];                                               \
    }                                                                        \
    fsc_ += __shfl_xor(fsc_, 16); fsc_ += __shfl_xor(fsc_, 32);              \
    msc_ += __shfl_xor(msc_, 16); msc_ += __shfl_xor(msc_, 32);              \
    if (l < 16) *(float2*)&s_part[G][lm][w * 2] = make_float2(fsc_, msc_);   \
} while (0)

    // PHASE_C: uses ambient nf_* locals for the state advance.
#define PHASE_C(G, S, PP, BM, TT) do {                                       \
    const f32x4 p0_ = *(const f32x4*)&s_part[G][lm][0];                      \
    const f32x4 p1_ = *(const f32x4*)&s_part[G][lm][4];                      \
    const f32x4 p2_ = *(const f32x4*)&s_part[G][lm][8];                      \
    const f32x4 p3_ = *(const f32x4*)&s_part[G][lm][12];                     \
    const float fsum_ = bfv + p0_.x + p0_.z + p1_.x + p1_.z                  \
                            + p2_.x + p2_.z + p3_.x + p3_.z;                 \
    const float msum_ = bmv + p0_.y + p0_.w + p1_.y + p1_.w                  \
                            + p2_.y + p2_.w + p3_.y + p3_.w;                 \
    const float f_sc_ = fminf(fmaxf(fsum_, -20.0f), 20.0f);                  \
    const float m_sc_ = fminf(fmaxf(msum_, -20.0f), 20.0f);                  \
    const float dsc_ = 5.0f * (f_sc_ - m_sc_);                               \
    const float ex_  = __expf(-fabsf(dsc_));                                 \
    const float inv_ = frcp(1.0f + ex_);                                     \
    const float fatt_ = (dsc_ >= 0.0f) ? inv_ : ex_ * inv_;                  \
    const float matt_ = 1.0f - fatt_;                                        \
    const float rr_ = (S).ego_v * (PP).inv_v0;                               \
    const float rr2_ = rr_ * rr_;                                            \
    const float base_ = (PP).amax * (1.0f - rr2_ * rr2_);                    \
    const float dxf_ = fminf(fmaxf((S).ef_dx, 0.1f), 500.0f);                \
    const float gapf_ = (PP).tg * (S).ego_v + (S).ego_v * (S).ef_dv * (PP).inv_gd; \
    const float dgf_ = (PP).jam + fmaxf(gapf_, 0.0f);                        \
    const float qf_ = dgf_ * frcp(dxf_);                                     \
    const float efa_ = fminf(fmaxf(base_ - (PP).amax * qf_ * qf_, -6.0f), 6.0f); \
    const float dxm_ = fminf(fmaxf((S).em_dx, 0.1f), 500.0f);                \
    const float gapm_ = (PP).tg * (S).ego_v + (S).ego_v * (S).em_dv * (PP).inv_gd; \
    const float dgm_ = (PP).jam + fmaxf(gapm_, 0.0f);                        \
    const float qm_ = dgm_ * frcp(dxm_);                                     \
    const float ema_ = fminf(fmaxf(base_ - (PP).amax * qm_ * qm_, -6.0f), 6.0f); \
    const float a2n_ = fatt_ * efa_ + matt_ * ema_;                          \
    const float delta_ = (S).ego_v * 0.1f + 0.005f * a2n_;                   \
    (S).disp  += delta_;                                                     \
    (S).ego_x += delta_;                                                     \
    (S).ego_v += a2n_ * 0.1f;                                                \
    (S).ego_a  = a2n_;                                                       \
    if (tid < 16) {                                                          \
        out_disp[(BM) * 51 + (TT) + 1] = (S).disp;                           \
        out_act [(BM) * 50 + (TT)]     = a2n_;                               \
        out_fat [(BM) * 50 + (TT)]     = fatt_;                              \
        out_mat [(BM) * 50 + (TT)]     = matt_;                              \
    }                                                                        \
    if ((TT) + 1 < NT) {                                                     \
        (S).ef_dx = nf_fx - (S).ego_x;                                       \
        (S).em_dx = (nf_mx - (S).ego_x) * nf_me + (1.0f - nf_me) * 100.0f;   \
        (S).ef_dv = (S).ego_v - nf_fv;                                       \
        (S).em_dv = ((S).ego_v - nf_mv) * nf_me;                             \
        (S).fa = nf_fa; (S).fv = nf_fv;                                      \
        (S).m0 = nf_m0; (S).m1 = nf_m1; (S).m2 = nf_m2;                      \
    }                                                                        \
} while (0)

    __syncthreads();              // s_w1d staged
    PHASE_A(0, st0, hp0);         // prologue: h1(g0, t=0)
    __syncthreads();

    for (int t = 0; t < NT; ++t) {
        // ---- interval I1: MFMA(g0) overlapped with dynamics+layer1(g1) ----
        {
            float nf_fv = 0, nf_mv = 0, nf_fx = 0, nf_mx = 0, nf_fa = 0, nf_me = 0;
            float nf_m0 = 0, nf_m1 = 0, nf_m2 = 0;
            if (t > 0) {   // exogenous for g1 advance (t-1 -> t)
                const float* sp = idm_s + (size_t)bm1 * 714 + t * 14;
                nf_fv = sp[1]; nf_mv = sp[2]; nf_fx = sp[4]; nf_mx = sp[5];
                nf_fa = sp[12]; nf_me = sp[13];
                const float* mp = merger_cs + (size_t)bm1 * 150 + t * 3;
                nf_m0 = mp[0]; nf_m1 = mp[1]; nf_m2 = mp[2];
            }
            PHASE_B(0);
            if (t > 0) PHASE_C(1, st1, pp1, bm1, t - 1);
            PHASE_A(1, st1, hp1);
        }
        __syncthreads();

        // ---- interval I2: MFMA(g1) overlapped with dynamics+layer1(g0) ----
        {
            float nf_fv = 0, nf_mv = 0, nf_fx = 0, nf_mx = 0, nf_fa = 0, nf_me = 0;
            float nf_m0 = 0, nf_m1 = 0, nf_m2 = 0;
            if (t + 1 < NT) {   // exogenous for g0 advance (t -> t+1)
                const float* sp = idm_s + (size_t)bm0 * 714 + (t + 1) * 14;
                nf_fv = sp[1]; nf_mv = sp[2]; nf_fx = sp[4]; nf_mx = sp[5];
                nf_fa = sp[12]; nf_me = sp[13];
                const float* mp = merger_cs + (size_t)bm0 * 150 + (t + 1) * 3;
                nf_m0 = mp[0]; nf_m1 = mp[1]; nf_m2 = mp[2];
            }
            PHASE_B(1);
            PHASE_C(0, st0, pp0, bm0, t);
            if (t + 1 < NT) PHASE_A(0, st0, hp0);
        }
        __syncthreads();
    }

    // ---- epilogue: finish g1 at t = NT-1 (s_part[1] valid after last barrier) ----
    {
        float nf_fv = 0, nf_mv = 0, nf_fx = 0, nf_mx = 0, nf_fa = 0, nf_me = 0;
        float nf_m0 = 0, nf_m1 = 0, nf_m2 = 0;
        (void)nf_fv; (void)nf_mv; (void)nf_fx; (void)nf_mx; (void)nf_fa;
        (void)nf_me; (void)nf_m0; (void)nf_m1; (void)nf_m2;
        PHASE_C(1, st1, pp1, bm1, NT - 1);
    }

#undef PHASE_A
#undef PHASE_B
#undef PHASE_C
}

extern "C" void kernel_launch(void* const* d_in, const int* in_sizes, int n_in,
                              void* d_out, int out_size, void* d_ws, size_t ws_size,
                              hipStream_t stream) {
    (void)in_sizes; (void)n_in; (void)d_ws; (void)ws_size; (void)out_size;
    const float* idm_params  = (const float*)d_in[0];
    const float* proj_latent = (const float*)d_in[1];
    const float* enc_h       = (const float*)d_in[2];
    const float* idm_s       = (const float*)d_in[3];
    const float* merger_cs   = (const float*)d_in[4];
    const float* scaler_mean = (const float*)d_in[5];
    const float* scaler_var  = (const float*)d_in[6];
    const float* W1          = (const float*)d_in[7];
    const float* b1          = (const float*)d_in[8];
    const float* W2          = (const float*)d_in[9];
    const float* b2          = (const float*)d_in[10];
    const float* Wf          = (const float*)d_in[11];
    const float* bfp         = (const float*)d_in[12];
    const float* Wm          = (const float*)d_in[13];
    const float* bmp         = (const float*)d_in[14];

    idm_rollout_kernel<<<dim3(NB / 32), dim3(512), 0, stream>>>(
        idm_params, proj_latent, enc_h, idm_s, merger_cs,
        scaler_mean, scaler_var, W1, b1, W2, b2, Wf, bfp, Wm, bmp,
        (float*)d_out);
}

// Round 12
// 208.421 us; speedup vs baseline: 1.2064x; 1.2064x over previous
//
#include <hip/hip_runtime.h>

#define NB 8192
#define NT 50

typedef short short8 __attribute__((ext_vector_type(8)));
typedef float f32x4 __attribute__((ext_vector_type(4)));

__device__ __forceinline__ float leaky(float x) { return x > 0.0f ? x : 0.3f * x; }

__device__ __forceinline__ unsigned short bf16rn(float v) {
    unsigned int u = __float_as_uint(v);
    unsigned int r = u + 0x7FFFu + ((u >> 16) & 1u);
    return (unsigned short)(r >> 16);
}
__device__ __forceinline__ float bf16tof(unsigned short h) {
    return __uint_as_float(((unsigned int)h) << 16);
}
__device__ __forceinline__ float frcp(float x) { return __builtin_amdgcn_rcpf(x); }

extern "C" __global__ __launch_bounds__(512, 2)
void idm_rollout_kernel(const float* __restrict__ idm_params,
                        const float* __restrict__ proj_latent,
                        const float* __restrict__ enc_h,
                        const float* __restrict__ idm_s,
                        const float* __restrict__ merger_cs,
                        const float* __restrict__ scaler_mean,
                        const float* __restrict__ scaler_var,
                        const float* __restrict__ W1,
                        const float* __restrict__ b1,
                        const float* __restrict__ W2,
                        const float* __restrict__ b2,
                        const float* __restrict__ Wf,
                        const float* __restrict__ bfp,
                        const float* __restrict__ Wm,
                        const float* __restrict__ bmp,
                        float* __restrict__ out)
{
    // h1 3-level fragments: [kchunk][lvl][slot-lane][e]
    __shared__ __align__(16) short s_a[4][3][64][8];       // 12 KB
    // head partials: [elem][2*jtile + {f,m}], padded row stride 20
    __shared__ __align__(16) float s_part[16][20];         // 1.25 KB

    const int tid = threadIdx.x;       // 0..511
    const int w   = tid >> 6;          // wave = jtile (layer2)
    const int l   = tid & 63;
    const int lm  = l & 15;            // this lane's batch element (within block)
    const int lq  = l >> 4;
    const int b0  = blockIdx.x * 16;
    const int bm  = b0 + lm;
    const int colbase = w * 16 + lq * 4;   // this lane's 4 h1/h2 columns

    // ---- dynamic W1 rows 256..266 at this lane's columns, in REGISTERS ----
    // env rows (r<8) pre-scaled by inv_std.
    f32x4 w1dreg[11];
    #pragma unroll
    for (int r = 0; r < 11; ++r) {
        f32x4 wq = *(const f32x4*)&W1[(256 + r) * 128 + colbase];
        if (r < 8) {
            const float is = 1.0f / sqrtf(scaler_var[r]);
            wq *= is;
        }
        w1dreg[r] = wq;
    }

    // ---- W2^T A-frags: ALL THREE levels in registers ----
    short8 W2T0[4], W2T1[4], W2L2[4];
    #pragma unroll
    for (int kc = 0; kc < 4; ++kc) {
        #pragma unroll
        for (int e = 0; e < 8; ++e) {
            const int k = kc * 32 + lq * 8 + e;
            const float v = W2[k * 128 + w * 16 + lm];
            const unsigned short q0 = bf16rn(v);
            const float r1 = v - bf16tof(q0);
            const unsigned short q1 = bf16rn(r1);
            W2T0[kc][e] = (short)q0; W2T1[kc][e] = (short)q1;
            W2L2[kc][e] = (short)bf16rn(r1 - bf16tof(q1));
        }
    }

    // ---- head constants for this lane's 4 cols ----
    const f32x4 b2r = *(const f32x4*)&b2[colbase];
    const f32x4 wfr = *(const f32x4*)&Wf[colbase];
    const f32x4 wmr = *(const f32x4*)&Wm[colbase];
    const float bfv = bfp[0];
    const float bmv = bmp[0];

    // ---- hpre for (elem lm, cols colbase..+3) ----
    f32x4 hp = *(const f32x4*)&b1[colbase];
    {
        const float* xl0 = proj_latent + (size_t)bm * 128;
        const float* xl1 = enc_h + (size_t)bm * 128;
        #pragma unroll 2
        for (int r0 = 0; r0 < 128; r0 += 4) {
            const f32x4 x = *(const f32x4*)&xl0[r0];
            #pragma unroll
            for (int j = 0; j < 4; ++j) {
                const f32x4 wq = *(const f32x4*)&W1[(r0 + j) * 128 + colbase];
                hp += x[j] * wq;
            }
        }
        #pragma unroll 2
        for (int r0 = 0; r0 < 128; r0 += 4) {
            const f32x4 x = *(const f32x4*)&xl1[r0];
            #pragma unroll
            for (int j = 0; j < 4; ++j) {
                const f32x4 wq = *(const f32x4*)&W1[(128 + r0 + j) * 128 + colbase];
                hp += x[j] * wq;
            }
        }
        #pragma unroll
        for (int rr = 0; rr < 8; ++rr) {   // fold -(mean*inv_std)@W1env (w1dreg pre-scaled)
            hp -= scaler_mean[rr] * w1dreg[rr];
        }
    }

    // ---- per-lane dynamics state for elem bm (redundant across lanes) ----
    float ego_v_r, ego_a_r, ego_x_r, disp_r;
    float ef_dv_r, ef_dx_r, em_dv_r, em_dx_r;
    float c_fa, c_fv, c_m0, c_m1, c_m2;
    {
        const float* sr = idm_s + (size_t)bm * 714;     // 51*14
        const float* mr = merger_cs + (size_t)bm * 150;
        ego_v_r = sr[0]; ego_a_r = sr[11]; ego_x_r = sr[3]; disp_r = 0.0f;
        const float fv0 = sr[1], mv0 = sr[2], fx0 = sr[4], mx0 = sr[5];
        c_fa = sr[12];
        const float me0 = sr[13];
        c_fv = fv0;
        ef_dx_r = fx0 - ego_x_r;
        em_dx_r = (mx0 - ego_x_r) * me0 + (1.0f - me0) * 100.0f;
        ef_dv_r = ego_v_r - fv0;
        em_dv_r = (ego_v_r - mv0) * me0;
        c_m0 = mr[0]; c_m1 = mr[1]; c_m2 = mr[2];
    }
    const float ptg    = idm_params[bm * 5 + 1];
    const float pjam   = idm_params[bm * 5 + 2];
    const float pamax  = idm_params[bm * 5 + 3];
    const float pinv_v0 = 1.0f / idm_params[bm * 5 + 0];
    const float pinv_gd = 1.0f / (2.0f * sqrtf(pamax * idm_params[bm * 5 + 4]));

    float* out_disp = out;
    float* out_act  = out + NB * 51;
    float* out_fat  = out + NB * (51 + 50);
    float* out_mat  = out + NB * (51 + 100);
    if (tid < 16) out_disp[bm * 51] = 0.0f;

    // producer slot for s_a writes (col -> consumer-fragment mapping)
    const int kcw = w >> 1;
    const int Lw  = lm + 16 * ((w & 1) * 2 + (lq >> 1));
    const int e0w = (lq & 1) * 4;

    for (int t = 0; t < NT; ++t) {
        // ---- prefetch next-step exogenous scalars (own elem) ----
        float nf_fv = 0, nf_mv = 0, nf_fx = 0, nf_mx = 0, nf_fa = 0, nf_me = 0;
        float nf_m0 = 0, nf_m1 = 0, nf_m2 = 0;
        if (t + 1 < NT) {
            const float* sp = idm_s + (size_t)bm * 714 + (t + 1) * 14;
            nf_fv = sp[1]; nf_mv = sp[2]; nf_fx = sp[4]; nf_mx = sp[5];
            nf_fa = sp[12]; nf_me = sp[13];
            const float* mp = merger_cs + (size_t)bm * 150 + (t + 1) * 3;
            nf_m0 = mp[0]; nf_m1 = mp[1]; nf_m2 = mp[2];
        }

        // ---- phase A: layer-1 via VALU, all operands in registers ----
        float ev[11];
        ev[0] = ego_a_r; ev[1] = c_fa;    ev[2] = ego_v_r; ev[3] = c_fv;
        ev[4] = ef_dv_r; ev[5] = ef_dx_r; ev[6] = em_dv_r; ev[7] = em_dx_r;
        ev[8] = c_m0;    ev[9] = c_m1;    ev[10] = c_m2;
        f32x4 hq = hp;
        #pragma unroll
        for (int r = 0; r < 11; ++r) hq += ev[r] * w1dreg[r];
        const float h0 = leaky(hq.x), h1v = leaky(hq.y);
        const float h2v = leaky(hq.z), h3 = leaky(hq.w);

        // 3-level truncation split (residuals exact); pack pairs
        const unsigned int HM = 0xFFFF0000u;
        unsigned int ua = __float_as_uint(h0), ub = __float_as_uint(h1v);
        unsigned int uc = __float_as_uint(h2v), ud = __float_as_uint(h3);
        const unsigned int w00 = (ua >> 16) | (ub & HM);
        const unsigned int w01 = (uc >> 16) | (ud & HM);
        const float r1a = h0  - __uint_as_float(ua & HM);
        const float r1b = h1v - __uint_as_float(ub & HM);
        const float r1c = h2v - __uint_as_float(uc & HM);
        const float r1d = h3  - __uint_as_float(ud & HM);
        ua = __float_as_uint(r1a); ub = __float_as_uint(r1b);
        uc = __float_as_uint(r1c); ud = __float_as_uint(r1d);
        const unsigned int w10 = (ua >> 16) | (ub & HM);
        const unsigned int w11 = (uc >> 16) | (ud & HM);
        const float r2a = r1a - __uint_as_float(ua & HM);
        const float r2b = r1b - __uint_as_float(ub & HM);
        const float r2c = r1c - __uint_as_float(uc & HM);
        const float r2d = r1d - __uint_as_float(ud & HM);
        const unsigned int w20 = (__float_as_uint(r2a) >> 16) | (__float_as_uint(r2b) & HM);
        const unsigned int w21 = (__float_as_uint(r2c) >> 16) | (__float_as_uint(r2d) & HM);
        *(uint2*)&s_a[kcw][0][Lw][e0w] = make_uint2(w00, w01);
        *(uint2*)&s_a[kcw][1][Lw][e0w] = make_uint2(w10, w11);
        *(uint2*)&s_a[kcw][2][Lw][e0w] = make_uint2(w20, w21);

        __syncthreads();   // B1: h1 fragments visible

        // ---- phase B: layer-2 via swapped MFMA (A=W2T regs, B=h1 frags) ----
        f32x4 aA = {0,0,0,0}, aB = {0,0,0,0}, aC = {0,0,0,0};
        #pragma unroll
        for (int kc = 0; kc < 4; ++kc) {
            const short8 x0 = *(const short8*)&s_a[kc][0][l][0];
            const short8 x1 = *(const short8*)&s_a[kc][1][l][0];
            const short8 x2 = *(const short8*)&s_a[kc][2][l][0];
            aA = __builtin_amdgcn_mfma_f32_16x16x32_bf16(W2T0[kc], x0, aA, 0, 0, 0);
            aB = __builtin_amdgcn_mfma_f32_16x16x32_bf16(W2T0[kc], x1, aB, 0, 0, 0);
            aB = __builtin_amdgcn_mfma_f32_16x16x32_bf16(W2T1[kc], x0, aB, 0, 0, 0);
            aC = __builtin_amdgcn_mfma_f32_16x16x32_bf16(W2T1[kc], x1, aC, 0, 0, 0);
            aC = __builtin_amdgcn_mfma_f32_16x16x32_bf16(W2T0[kc], x2, aC, 0, 0, 0);
            aC = __builtin_amdgcn_mfma_f32_16x16x32_bf16(W2L2[kc], x0, aC, 0, 0, 0);
        }
        // lane holds h2[elem=lm][j=colbase+r] -> partial head scores
        float fsc = 0.0f, msc = 0.0f;
        #pragma unroll
        for (int r = 0; r < 4; ++r) {
            const float h2 = leaky(aA[r] + aB[r] + aC[r] + b2r[r]);
            fsc += h2 * wfr[r];
            msc += h2 * wmr[r];
        }
        // reduce over lq (lanes lm, lm+16, lm+32, lm+48)
        fsc += __shfl_xor(fsc, 16); fsc += __shfl_xor(fsc, 32);
        msc += __shfl_xor(msc, 16); msc += __shfl_xor(msc, 32);
        if (l < 16) *(float2*)&s_part[lm][w * 2] = make_float2(fsc, msc);

        __syncthreads();   // B2: head partials visible

        // ---- phase C: dynamics, redundant on all lanes (own elem bm) ----
        {
            const f32x4 p0 = *(const f32x4*)&s_part[lm][0];
            const f32x4 p1 = *(const f32x4*)&s_part[lm][4];
            const f32x4 p2 = *(const f32x4*)&s_part[lm][8];
            const f32x4 p3 = *(const f32x4*)&s_part[lm][12];
            const float fsum = bfv + p0.x + p0.z + p1.x + p1.z + p2.x + p2.z + p3.x + p3.z;
            const float msum = bmv + p0.y + p0.w + p1.y + p1.w + p2.y + p2.w + p3.y + p3.w;

            const float f_sc = fminf(fmaxf(fsum, -20.0f), 20.0f);
            const float m_sc = fminf(fmaxf(msum, -20.0f), 20.0f);
            const float dsc = 5.0f * (f_sc - m_sc);
            const float ex  = __expf(-fabsf(dsc));
            const float inv = frcp(1.0f + ex);
            const float fatt = (dsc >= 0.0f) ? inv : ex * inv;
            const float matt = 1.0f - fatt;

            // shared IDM terms
            const float rr_ = ego_v_r * pinv_v0;
            const float rr2 = rr_ * rr_;
            const float base = pamax * (1.0f - rr2 * rr2);
            // follower branch
            const float dxf = fminf(fmaxf(ef_dx_r, 0.1f), 500.0f);
            const float gapf = ptg * ego_v_r + ego_v_r * ef_dv_r * pinv_gd;
            const float dgf = pjam + fmaxf(gapf, 0.0f);
            const float qf = dgf * frcp(dxf);
            const float efa = fminf(fmaxf(base - pamax * qf * qf, -6.0f), 6.0f);
            // merger branch
            const float dxm = fminf(fmaxf(em_dx_r, 0.1f), 500.0f);
            const float gapm = ptg * ego_v_r + ego_v_r * em_dv_r * pinv_gd;
            const float dgm = pjam + fmaxf(gapm, 0.0f);
            const float qm = dgm * frcp(dxm);
            const float ema = fminf(fmaxf(base - pamax * qm * qm, -6.0f), 6.0f);

            const float a2n = fatt * efa + matt * ema;

            const float delta = ego_v_r * 0.1f + 0.005f * a2n;
            disp_r  += delta;
            ego_x_r += delta;
            ego_v_r += a2n * 0.1f;
            ego_a_r  = a2n;

            if (tid < 16) {
                out_disp[bm * 51 + t + 1] = disp_r;
                out_act [bm * 50 + t]     = a2n;
                out_fat [bm * 50 + t]     = fatt;
                out_mat [bm * 50 + t]     = matt;
            }

            if (t + 1 < NT) {
                ef_dx_r = nf_fx - ego_x_r;
                em_dx_r = (nf_mx - ego_x_r) * nf_me + (1.0f - nf_me) * 100.0f;
                ef_dv_r = ego_v_r - nf_fv;
                em_dv_r = (ego_v_r - nf_mv) * nf_me;
                c_fa = nf_fa; c_fv = nf_fv;
                c_m0 = nf_m0; c_m1 = nf_m1; c_m2 = nf_m2;
            }
        }
        // no 3rd barrier: s_a rewrite (t+1) is fenced by B2;
        // s_part rewrite (t+1) is fenced by B1(t+1).
    }
}

extern "C" void kernel_launch(void* const* d_in, const int* in_sizes, int n_in,
                              void* d_out, int out_size, void* d_ws, size_t ws_size,
                              hipStream_t stream) {
    (void)in_sizes; (void)n_in; (void)d_ws; (void)ws_size; (void)out_size;
    const float* idm_params  = (const float*)d_in[0];
    const float* proj_latent = (const float*)d_in[1];
    const float* enc_h       = (const float*)d_in[2];
    const float* idm_s       = (const float*)d_in[3];
    const float* merger_cs   = (const float*)d_in[4];
    const float* scaler_mean = (const float*)d_in[5];
    const float* scaler_var  = (const float*)d_in[6];
    const float* W1          = (const float*)d_in[7];
    const float* b1          = (const float*)d_in[8];
    const float* W2          = (const float*)d_in[9];
    const float* b2          = (const float*)d_in[10];
    const float* Wf          = (const float*)d_in[11];
    const float* bfp         = (const float*)d_in[12];
    const float* Wm          = (const float*)d_in[13];
    const float* bmp         = (const float*)d_in[14];

    idm_rollout_kernel<<<dim3(NB / 16), dim3(512), 0, stream>>>(
        idm_params, proj_latent, enc_h, idm_s, merger_cs,
        scaler_mean, scaler_var, W1, b1, W2, b2, Wf, bfp, Wm, bmp,
        (float*)d_out);
}

// Round 13
// 176.790 us; speedup vs baseline: 1.4222x; 1.1789x over previous
//
#include <hip/hip_runtime.h>

#define NB 8192
#define NT 50

typedef short short8 __attribute__((ext_vector_type(8)));
typedef float f32x4 __attribute__((ext_vector_type(4)));

__device__ __forceinline__ float leaky(float x) { return x > 0.0f ? x : 0.3f * x; }

__device__ __forceinline__ unsigned short bf16rn(float v) {
    unsigned int u = __float_as_uint(v);
    unsigned int r = u + 0x7FFFu + ((u >> 16) & 1u);
    return (unsigned short)(r >> 16);
}
__device__ __forceinline__ float bf16tof(unsigned short h) {
    return __uint_as_float(((unsigned int)h) << 16);
}
__device__ __forceinline__ float frcp(float x) { return __builtin_amdgcn_rcpf(x); }

extern "C" __global__ __launch_bounds__(256, 2)
void idm_rollout_kernel(const float* __restrict__ idm_params,
                        const float* __restrict__ proj_latent,
                        const float* __restrict__ enc_h,
                        const float* __restrict__ idm_s,
                        const float* __restrict__ merger_cs,
                        const float* __restrict__ scaler_mean,
                        const float* __restrict__ scaler_var,
                        const float* __restrict__ W1,
                        const float* __restrict__ b1,
                        const float* __restrict__ W2,
                        const float* __restrict__ b2,
                        const float* __restrict__ Wf,
                        const float* __restrict__ bfp,
                        const float* __restrict__ Wm,
                        const float* __restrict__ bmp,
                        float* __restrict__ out)
{
    // h1 3-level fragments: [kchunk][lvl][lane][e]  (identity slot map)
    __shared__ __align__(16) short s_a[4][3][64][8];       // 12 KB
    // dynamic W1 rows 256..266 (env rows pre-scaled by inv_std)
    __shared__ __align__(16) float s_w1d[11][128];         // 5.5 KB
    // head partials: [elem][2*w + {f,m}], padded row stride 12
    __shared__ __align__(16) float s_part[16][12];         // 0.75 KB

    const int tid = threadIdx.x;       // 0..255
    const int w   = tid >> 6;          // wave 0..3
    const int l   = tid & 63;
    const int lm  = l & 15;            // this lane's batch element (within block)
    const int lq  = l >> 4;
    const int b0  = blockIdx.x * 16;
    const int bm  = b0 + lm;
    const int c0  = w * 32 + lq * 8;   // this lane's 8 layer-1 columns (= consumer slice kc=w)

    // ---- stage dynamic W1 rows; env rows scaled by inv_std ----
    for (int idx = tid; idx < 11 * 128; idx += 256) {
        const int r = idx >> 7, c = idx & 127;
        float wv_ = W1[(256 + r) * 128 + c];
        if (r < 8) wv_ *= 1.0f / sqrtf(scaler_var[r]);
        s_w1d[r][c] = wv_;
    }

    // ---- W2^T A-frags for 2 jtiles, ALL THREE levels in registers ----
    short8 W2T0[2][4], W2T1[2][4], W2L2[2][4];
    #pragma unroll
    for (int jt = 0; jt < 2; ++jt) {
        const int jtg = 2 * w + jt;
        #pragma unroll
        for (int kc = 0; kc < 4; ++kc) {
            #pragma unroll
            for (int e = 0; e < 8; ++e) {
                const int k = kc * 32 + lq * 8 + e;
                const float v = W2[k * 128 + jtg * 16 + lm];
                const unsigned short q0 = bf16rn(v);
                const float r1 = v - bf16tof(q0);
                const unsigned short q1 = bf16rn(r1);
                W2T0[jt][kc][e] = (short)q0; W2T1[jt][kc][e] = (short)q1;
                W2L2[jt][kc][e] = (short)bf16rn(r1 - bf16tof(q1));
            }
        }
    }

    // ---- head constants for this lane's D cols (2 jtiles) ----
    f32x4 b2r[2], wfr[2], wmr[2];
    #pragma unroll
    for (int jt = 0; jt < 2; ++jt) {
        const int cb = (2 * w + jt) * 16 + lq * 4;
        b2r[jt] = *(const f32x4*)&b2[cb];
        wfr[jt] = *(const f32x4*)&Wf[cb];
        wmr[jt] = *(const f32x4*)&Wm[cb];
    }
    const float bfv = bfp[0];
    const float bmv = bmp[0];

    __syncthreads();   // s_w1d staged (needed by hpre fold below)

    // ---- hpre for (elem lm, cols c0..c0+7) ----
    f32x4 hpA = *(const f32x4*)&b1[c0];
    f32x4 hpB = *(const f32x4*)&b1[c0 + 4];
    {
        const float* xl0 = proj_latent + (size_t)bm * 128;
        const float* xl1 = enc_h + (size_t)bm * 128;
        #pragma unroll 2
        for (int r0 = 0; r0 < 128; r0 += 4) {
            const f32x4 x = *(const f32x4*)&xl0[r0];
            #pragma unroll
            for (int j = 0; j < 4; ++j) {
                hpA += x[j] * *(const f32x4*)&W1[(r0 + j) * 128 + c0];
                hpB += x[j] * *(const f32x4*)&W1[(r0 + j) * 128 + c0 + 4];
            }
        }
        #pragma unroll 2
        for (int r0 = 0; r0 < 128; r0 += 4) {
            const f32x4 x = *(const f32x4*)&xl1[r0];
            #pragma unroll
            for (int j = 0; j < 4; ++j) {
                hpA += x[j] * *(const f32x4*)&W1[(128 + r0 + j) * 128 + c0];
                hpB += x[j] * *(const f32x4*)&W1[(128 + r0 + j) * 128 + c0 + 4];
            }
        }
        #pragma unroll
        for (int rr = 0; rr < 8; ++rr) {   // fold -(mean*inv_std)@W1env (s_w1d pre-scaled)
            const float c = scaler_mean[rr];
            hpA -= c * *(const f32x4*)&s_w1d[rr][c0];
            hpB -= c * *(const f32x4*)&s_w1d[rr][c0 + 4];
        }
    }

    // ---- per-lane dynamics state for elem bm (redundant x16) ----
    float ego_v_r, ego_a_r, ego_x_r, disp_r;
    float ef_dv_r, ef_dx_r, em_dv_r, em_dx_r;
    float c_fa, c_fv, c_m0, c_m1, c_m2;
    {
        const float* sr = idm_s + (size_t)bm * 714;     // 51*14
        const float* mr = merger_cs + (size_t)bm * 150;
        ego_v_r = sr[0]; ego_a_r = sr[11]; ego_x_r = sr[3]; disp_r = 0.0f;
        const float fv0 = sr[1], mv0 = sr[2], fx0 = sr[4], mx0 = sr[5];
        c_fa = sr[12];
        const float me0 = sr[13];
        c_fv = fv0;
        ef_dx_r = fx0 - ego_x_r;
        em_dx_r = (mx0 - ego_x_r) * me0 + (1.0f - me0) * 100.0f;
        ef_dv_r = ego_v_r - fv0;
        em_dv_r = (ego_v_r - mv0) * me0;
        c_m0 = mr[0]; c_m1 = mr[1]; c_m2 = mr[2];
    }
    const float ptg    = idm_params[bm * 5 + 1];
    const float pjam   = idm_params[bm * 5 + 2];
    const float pamax  = idm_params[bm * 5 + 3];
    const float pinv_v0 = 1.0f / idm_params[bm * 5 + 0];
    const float pinv_gd = 1.0f / (2.0f * sqrtf(pamax * idm_params[bm * 5 + 4]));

    float* out_disp = out;
    float* out_act  = out + NB * 51;
    float* out_fat  = out + NB * (51 + 50);
    float* out_mat  = out + NB * (51 + 100);
    if (tid < 16) out_disp[bm * 51] = 0.0f;

    for (int t = 0; t < NT; ++t) {
        // ---- prefetch next-step exogenous scalars (own elem) ----
        float nf_fv = 0, nf_mv = 0, nf_fx = 0, nf_mx = 0, nf_fa = 0, nf_me = 0;
        float nf_m0 = 0, nf_m1 = 0, nf_m2 = 0;
        if (t + 1 < NT) {
            const float* sp = idm_s + (size_t)bm * 714 + (t + 1) * 14;
            nf_fv = sp[1]; nf_mv = sp[2]; nf_fx = sp[4]; nf_mx = sp[5];
            nf_fa = sp[12]; nf_me = sp[13];
            const float* mp = merger_cs + (size_t)bm * 150 + (t + 1) * 3;
            nf_m0 = mp[0]; nf_m1 = mp[1]; nf_m2 = mp[2];
        }

        // ---- phase A: layer-1 via VALU (8 cols, 11 dyn rows from LDS) ----
        float ev[11];
        ev[0] = ego_a_r; ev[1] = c_fa;    ev[2] = ego_v_r; ev[3] = c_fv;
        ev[4] = ef_dv_r; ev[5] = ef_dx_r; ev[6] = em_dv_r; ev[7] = em_dx_r;
        ev[8] = c_m0;    ev[9] = c_m1;    ev[10] = c_m2;
        f32x4 hqA = hpA, hqB = hpB;
        #pragma unroll
        for (int r = 0; r < 11; ++r) {
            hqA += ev[r] * *(const f32x4*)&s_w1d[r][c0];
            hqB += ev[r] * *(const f32x4*)&s_w1d[r][c0 + 4];
        }
        float h[8];
        h[0] = leaky(hqA.x); h[1] = leaky(hqA.y); h[2] = leaky(hqA.z); h[3] = leaky(hqA.w);
        h[4] = leaky(hqB.x); h[5] = leaky(hqB.y); h[6] = leaky(hqB.z); h[7] = leaky(hqB.w);

        // 3-level truncation split; this lane's 8 cols == its consumer slice (kc=w)
        short8 A0, A1, A2;
        const unsigned int HM = 0xFFFF0000u;
        #pragma unroll
        for (int e = 0; e < 8; ++e) {
            const float v = h[e];
            const unsigned int u0 = __float_as_uint(v);
            A0[e] = (short)(u0 >> 16);
            const float r1 = v - __uint_as_float(u0 & HM);
            const unsigned int u1 = __float_as_uint(r1);
            A1[e] = (short)(u1 >> 16);
            const float r2 = r1 - __uint_as_float(u1 & HM);
            A2[e] = (short)(__float_as_uint(r2) >> 16);
        }
        *(short8*)&s_a[w][0][l][0] = A0;
        *(short8*)&s_a[w][1][l][0] = A1;
        *(short8*)&s_a[w][2][l][0] = A2;

        __syncthreads();   // B1: h1 fragments visible (4-wave domain)

        // ---- phase B: layer-2 via swapped MFMA, 2 jtiles per wave ----
        f32x4 aA[2], aB[2], aC[2];
        #pragma unroll
        for (int jt = 0; jt < 2; ++jt) {
            aA[jt] = f32x4{0,0,0,0}; aB[jt] = f32x4{0,0,0,0}; aC[jt] = f32x4{0,0,0,0};
        }
        #pragma unroll
        for (int kc = 0; kc < 4; ++kc) {
            const short8 x0 = *(const short8*)&s_a[kc][0][l][0];
            const short8 x1 = *(const short8*)&s_a[kc][1][l][0];
            const short8 x2 = *(const short8*)&s_a[kc][2][l][0];
            #pragma unroll
            for (int jt = 0; jt < 2; ++jt) {
                aA[jt] = __builtin_amdgcn_mfma_f32_16x16x32_bf16(W2T0[jt][kc], x0, aA[jt], 0, 0, 0);
                aB[jt] = __builtin_amdgcn_mfma_f32_16x16x32_bf16(W2T0[jt][kc], x1, aB[jt], 0, 0, 0);
                aB[jt] = __builtin_amdgcn_mfma_f32_16x16x32_bf16(W2T1[jt][kc], x0, aB[jt], 0, 0, 0);
                aC[jt] = __builtin_amdgcn_mfma_f32_16x16x32_bf16(W2T1[jt][kc], x1, aC[jt], 0, 0, 0);
                aC[jt] = __builtin_amdgcn_mfma_f32_16x16x32_bf16(W2T0[jt][kc], x2, aC[jt], 0, 0, 0);
                aC[jt] = __builtin_amdgcn_mfma_f32_16x16x32_bf16(W2L2[jt][kc], x0, aC[jt], 0, 0, 0);
            }
        }
        // heads: lane holds h2[elem=lm][cols jt*16+lq*4+r] for its 2 jtiles
        float fsc = 0.0f, msc = 0.0f;
        #pragma unroll
        for (int jt = 0; jt < 2; ++jt) {
            #pragma unroll
            for (int r = 0; r < 4; ++r) {
                const float h2 = leaky(aA[jt][r] + aB[jt][r] + aC[jt][r] + b2r[jt][r]);
                fsc += h2 * wfr[jt][r];
                msc += h2 * wmr[jt][r];
            }
        }
        // reduce over lq (xor16/32); after both, all lq copies hold the full sum
        fsc += __shfl_xor(fsc, 16); fsc += __shfl_xor(fsc, 32);
        msc += __shfl_xor(msc, 16); msc += __shfl_xor(msc, 32);
        if (l < 16) *(float2*)&s_part[lm][w * 2] = make_float2(fsc, msc);

        __syncthreads();   // B2: head partials visible

        // ---- phase C: dynamics, redundant on all lanes (own elem bm) ----
        {
            const f32x4 p0 = *(const f32x4*)&s_part[lm][0];
            const f32x4 p1 = *(const f32x4*)&s_part[lm][4];
            const float fsum = bfv + p0.x + p0.z + p1.x + p1.z;
            const float msum = bmv + p0.y + p0.w + p1.y + p1.w;

            const float f_sc = fminf(fmaxf(fsum, -20.0f), 20.0f);
            const float m_sc = fminf(fmaxf(msum, -20.0f), 20.0f);
            const float dsc = 5.0f * (f_sc - m_sc);
            const float ex  = __expf(-fabsf(dsc));
            const float inv = frcp(1.0f + ex);
            const float fatt = (dsc >= 0.0f) ? inv : ex * inv;
            const float matt = 1.0f - fatt;

            // shared IDM terms
            const float rr_ = ego_v_r * pinv_v0;
            const float rr2 = rr_ * rr_;
            const float base = pamax * (1.0f - rr2 * rr2);
            // follower branch
            const float dxf = fminf(fmaxf(ef_dx_r, 0.1f), 500.0f);
            const float gapf = ptg * ego_v_r + ego_v_r * ef_dv_r * pinv_gd;
            const float dgf = pjam + fmaxf(gapf, 0.0f);
            const float qf = dgf * frcp(dxf);
            const float efa = fminf(fmaxf(base - pamax * qf * qf, -6.0f), 6.0f);
            // merger branch
            const float dxm = fminf(fmaxf(em_dx_r, 0.1f), 500.0f);
            const float gapm = ptg * ego_v_r + ego_v_r * em_dv_r * pinv_gd;
            const float dgm = pjam + fmaxf(gapm, 0.0f);
            const float qm = dgm * frcp(dxm);
            const float ema = fminf(fmaxf(base - pamax * qm * qm, -6.0f), 6.0f);

            const float a2n = fatt * efa + matt * ema;

            const float delta = ego_v_r * 0.1f + 0.005f * a2n;
            disp_r  += delta;
            ego_x_r += delta;
            ego_v_r += a2n * 0.1f;
            ego_a_r  = a2n;

            if (tid < 16) {
                out_disp[bm * 51 + t + 1] = disp_r;
                out_act [bm * 50 + t]     = a2n;
                out_fat [bm * 50 + t]     = fatt;
                out_mat [bm * 50 + t]     = matt;
            }

            if (t + 1 < NT) {
                ef_dx_r = nf_fx - ego_x_r;
                em_dx_r = (nf_mx - ego_x_r) * nf_me + (1.0f - nf_me) * 100.0f;
                ef_dv_r = ego_v_r - nf_fv;
                em_dv_r = (ego_v_r - nf_mv) * nf_me;
                c_fa = nf_fa; c_fv = nf_fv;
                c_m0 = nf_m0; c_m1 = nf_m1; c_m2 = nf_m2;
            }
        }
        // no 3rd barrier: s_a rewrite (t+1) is fenced by B2;
        // s_part rewrite (t+1) is fenced by B1(t+1).
    }
}

extern "C" void kernel_launch(void* const* d_in, const int* in_sizes, int n_in,
                              void* d_out, int out_size, void* d_ws, size_t ws_size,
                              hipStream_t stream) {
    (void)in_sizes; (void)n_in; (void)d_ws; (void)ws_size; (void)out_size;
    const float* idm_params  = (const float*)d_in[0];
    const float* proj_latent = (const float*)d_in[1];
    const float* enc_h       = (const float*)d_in[2];
    const float* idm_s       = (const float*)d_in[3];
    const float* merger_cs   = (const float*)d_in[4];
    const float* scaler_mean = (const float*)d_in[5];
    const float* scaler_var  = (const float*)d_in[6];
    const float* W1          = (const float*)d_in[7];
    const float* b1          = (const float*)d_in[8];
    const float* W2          = (const float*)d_in[9];
    const float* b2          = (const float*)d_in[10];
    const float* Wf          = (const float*)d_in[11];
    const float* bfp         = (const float*)d_in[12];
    const float* Wm          = (const float*)d_in[13];
    const float* bmp         = (const float*)d_in[14];

    idm_rollout_kernel<<<dim3(NB / 16), dim3(256), 0, stream>>>(
        idm_params, proj_latent, enc_h, idm_s, merger_cs,
        scaler_mean, scaler_var, W1, b1, W2, b2, Wf, bfp, Wm, bmp,
        (float*)d_out);
}